// Round 5
// baseline (439.682 us; speedup 1.0000x reference)
//
#include <hip/hip_runtime.h>
#include <cstdint>

#define WID   160
#define HEI   160
#define HWPIX (WID * HEI)   // 25600
#define CIN_  64
#define COUT_ 64
#define BATCH 32
#define PW    162           // padded width/height (zero border)
#define PPIX  (PW * PW)     // 26244
#define NBORDER 636         // 2*160 + 2*158 border pixels per image

// ---------------------------------------------------------------------------
// Kernel 1: weight prep. One wave per output channel. lane = ci.
// wpack[co][tap] bit ci = (w>0); alpha[co] = mean(|clip(w,-1,1)|).
// ---------------------------------------------------------------------------
__global__ __launch_bounds__(64) void wprep_kernel(const float* __restrict__ w,
                                                   uint64_t* __restrict__ wpack,
                                                   float* __restrict__ alpha) {
    const int co = blockIdx.x;
    const int ci = threadIdx.x;
    const float* wp = w + ((size_t)co * CIN_ + ci) * 9;

    float vals[9];
    float s = 0.0f;
#pragma unroll
    for (int t = 0; t < 9; ++t) {
        float v = wp[t];
        vals[t] = v;
        s += fminf(fabsf(v), 1.0f);
    }
#pragma unroll
    for (int t = 0; t < 9; ++t) {
        unsigned long long m = __ballot(vals[t] > 0.0f);
        if (ci == 0) wpack[co * 9 + t] = m;
    }
#pragma unroll
    for (int off = 32; off > 0; off >>= 1) s += __shfl_down(s, off);
    if (ci == 0) alpha[co] = s * (1.0f / 576.0f);
}

// ---------------------------------------------------------------------------
// Kernel 2: binarize + channel-pack, CHANNEL-SPLIT x4 (blockIdx.z = quarter).
// Thread = 4 consecutive pixels x 16 channels -> u16 partial word written
// byte-exactly into its quarter of the u64 cell (little-endian: bits
// 16q..16q+15 == u16 at offset q; disjoint bytes across blocks -> race-free).
// Grid 3200 blocks / 12800 waves (was 800/3200): the old version was
// latency-bound (~1-2 TB/s, round-3 evidence) on 64 strided loads/thread.
// Block (x=0, z=0) also zeroes the 644 border cells (replaces memset).
// ---------------------------------------------------------------------------
__global__ __launch_bounds__(256) void binpack_kernel(const float* __restrict__ x,
                                                      uint64_t* __restrict__ packed) {
    const int t = blockIdx.x * 256 + threadIdx.x;    // group id 0..6399
    const int b = blockIdx.y;
    const int q = blockIdx.z;                        // channel quarter 0..3
    uint64_t* pimg = packed + (size_t)b * PPIX;

    // border zeroing: rows 0 and 161, cols 0 and 161 (u64 cells)
    if (blockIdx.x == 0 && q == 0) {
        for (int j = threadIdx.x; j < PW; j += 256) {
            pimg[j] = 0;                              // top padded row
            pimg[(size_t)(PW - 1) * PW + j] = 0;      // bottom padded row
        }
        for (int r = threadIdx.x; r < HEI; r += 256) {
            pimg[(size_t)(r + 1) * PW] = 0;           // left padded col
            pimg[(size_t)(r + 1) * PW + (PW - 1)] = 0;// right padded col
        }
    }

    const int p4 = t * 4;
    const int y  = p4 / WID;
    const int x0 = p4 - y * WID;
    const float4* xp = (const float4*)(x + (size_t)b * CIN_ * HWPIX
                                         + (size_t)q * 16 * HWPIX + p4);

    uint32_t m0 = 0, m1 = 0, m2 = 0, m3 = 0;
#pragma unroll
    for (int ci = 0; ci < 16; ++ci) {
        float4 v = xp[(size_t)ci * (HWPIX / 4)];
        m0 |= (uint32_t)(v.x > 0.0f) << ci;
        m1 |= (uint32_t)(v.y > 0.0f) << ci;
        m2 |= (uint32_t)(v.z > 0.0f) << ci;
        m3 |= (uint32_t)(v.w > 0.0f) << ci;
    }
    // u16 view of the padded u64 cells: cell i, quarter q -> u16 index i*4+q
    uint16_t* dst = (uint16_t*)(pimg + (size_t)(y + 1) * PW + (x0 + 1));
    dst[0 * 4 + q] = (uint16_t)m0;
    dst[1 * 4 + q] = (uint16_t)m1;
    dst[2 * 4 + q] = (uint16_t)m2;
    dst[3 * 4 + q] = (uint16_t)m3;
}

// ---------------------------------------------------------------------------
// Kernel 3: main conv. Thread = FOUR consecutive pixels in one row (x%4==0,
// 16B-aligned float4 store, never crosses a row). Loads the 3x6 padded tap
// window ONCE, loops all 64 co with wave-uniform (scalar) weight loads
// amortized over 4 pixels. No bounds checks (zero pad); border ring is wrong
// here and overwritten by fixup_kernel.
// ---------------------------------------------------------------------------
__global__ __launch_bounds__(256) void conv_kernel(const uint64_t* __restrict__ packed,
                                                   const uint64_t* __restrict__ wpack,
                                                   const float* __restrict__ alpha,
                                                   float* __restrict__ out) {
    const int t4 = blockIdx.x * 256 + threadIdx.x;   // 0..6399 per image
    const int b  = blockIdx.y;
    const int p0 = t4 * 4;                 // first pixel of this thread
    const int y  = p0 / WID;
    const int x  = p0 - y * WID;           // x in {0,4,...,156}
    const uint64_t* pb = packed + (size_t)b * PPIX + (size_t)y * PW + x;

    uint64_t p[3][6];
#pragma unroll
    for (int ky = 0; ky < 3; ++ky)
#pragma unroll
        for (int kx = 0; kx < 6; ++kx)
            p[ky][kx] = pb[(size_t)ky * PW + kx];

    float* op = out + (size_t)b * COUT_ * HWPIX + p0;
#pragma unroll 4
    for (int co = 0; co < COUT_; ++co) {
        const uint64_t* wp = wpack + co * 9;
        int pc0 = 0, pc1 = 0, pc2 = 0, pc3 = 0;
#pragma unroll
        for (int ky = 0; ky < 3; ++ky)
#pragma unroll
            for (int kx = 0; kx < 3; ++kx) {
                const uint64_t ww = wp[ky * 3 + kx];   // wave-uniform -> s_load
                pc0 += __popcll(p[ky][kx + 0] ^ ww);
                pc1 += __popcll(p[ky][kx + 1] ^ ww);
                pc2 += __popcll(p[ky][kx + 2] ^ ww);
                pc3 += __popcll(p[ky][kx + 3] ^ ww);
            }
        const float a = alpha[co];
        const float c = 576.0f * a;
        const float m = -2.0f * a;
        float4 r;
        r.x = fmaf((float)pc0, m, c);
        r.y = fmaf((float)pc1, m, c);
        r.z = fmaf((float)pc2, m, c);
        r.w = fmaf((float)pc3, m, c);
        *(float4*)(op + (size_t)co * HWPIX) = r;       // 16B-aligned, coalesced
    }
}

// ---------------------------------------------------------------------------
// Kernel 4: exact recompute of the 636-pixel border ring, CO-PARALLEL:
// thread = one (border-pixel, co) pair; blockIdx.y = co (wave-uniform
// weight s_loads). ~20k waves vs 318 serial-co before.
// ---------------------------------------------------------------------------
__global__ __launch_bounds__(256) void fixup_kernel(const uint64_t* __restrict__ packed,
                                                    const uint64_t* __restrict__ wpack,
                                                    const float* __restrict__ alpha,
                                                    float* __restrict__ out) {
    const int t = blockIdx.x * 256 + threadIdx.x;
    if (t >= NBORDER * BATCH) return;
    const int co = blockIdx.y;
    const int b  = t / NBORDER;
    const int i  = t - b * NBORDER;
    int x, y;
    if      (i < 160) { y = 0;       x = i;       }
    else if (i < 320) { y = 159;     x = i - 160; }
    else if (i < 478) { x = 0;       y = i - 319; }  // y = 1..158
    else              { x = 159;     y = i - 477; }  // y = 1..158

    const uint64_t* pb = packed + (size_t)b * PPIX + (size_t)y * PW + x;
    const uint64_t* wp = wpack + co * 9;
    int pc = 0, nv = 0;
#pragma unroll
    for (int ky = 0; ky < 3; ++ky)
#pragma unroll
        for (int kx = 0; kx < 3; ++kx) {
            const int yy = y + ky - 1, xx = x + kx - 1;
            const int v = (yy >= 0) && (yy < HEI) && (xx >= 0) && (xx < WID);
            const uint64_t pt = pb[(size_t)ky * PW + kx];  // in-bounds (pad ring)
            nv += v;
            pc += v ? __popcll(pt ^ wp[ky * 3 + kx]) : 0;
        }
    out[(size_t)b * COUT_ * HWPIX + (size_t)co * HWPIX + (size_t)y * WID + x] =
        alpha[co] * (float)((nv << 6) - 2 * pc);
}

// ---------------------------------------------------------------------------
extern "C" void kernel_launch(void* const* d_in, const int* in_sizes, int n_in,
                              void* d_out, int out_size, void* d_ws, size_t ws_size,
                              hipStream_t stream) {
    const float* x = (const float*)d_in[0];  // [32,64,160,160] f32
    const float* w = (const float*)d_in[1];  // [64,64,3,3] f32
    float* out = (float*)d_out;              // [32,64,160,160] f32

    uint64_t* wpack  = (uint64_t*)d_ws;                      // 4608 B
    float*    alpha  = (float*)((char*)d_ws + 4608);         // 256 B
    uint64_t* packed = (uint64_t*)((char*)d_ws + 8192);      // 32*26244*8 = 6.72 MB

    // no memset: binpack block (0, b, 0) zeroes the padded border ring.

    wprep_kernel<<<dim3(COUT_), dim3(64), 0, stream>>>(w, wpack, alpha);
    binpack_kernel<<<dim3(HWPIX / 4 / 256, BATCH, 4), dim3(256), 0, stream>>>(x, packed);
    conv_kernel<<<dim3(HWPIX / 4 / 256, BATCH), dim3(256), 0, stream>>>(packed, wpack, alpha, out);
    fixup_kernel<<<dim3((NBORDER * BATCH + 255) / 256, COUT_), dim3(256), 0, stream>>>(packed, wpack, alpha, out);
}